// Round 21
// baseline (265.809 us; speedup 1.0000x reference)
//
#include <hip/hip_runtime.h>

#define NBATCH 8
#define NN     207
#define DHID   256
#define LL     2484      // 12*207
#define LLP    2496      // padded to multiple of 32
#define RT     24        // query rows per block (104 blocks/batch: 104*24=2496)
#define NBLK   104
#define GCOL8  2496      // u8 G-tile cols (j^swz stays within 64-aligned block)
#define TILES  78        // LLP/32
#define TPW    10        // j-tiles per wave (8 waves x 10 >= 78)
#define LNEPS  1e-5f

typedef __attribute__((ext_vector_type(8)))  short bf16x8;
typedef __attribute__((ext_vector_type(8)))  unsigned char u8x8;
typedef __attribute__((ext_vector_type(16))) float f32x16;

__device__ __forceinline__ short f2bf(float f) {
    unsigned u = __float_as_uint(f);
    unsigned r = (u + 0x7FFFu + ((u >> 16) & 1u)) >> 16;
    return (short)r;
}

// ---------------- Kernel 1: LayerNorm + Q/K projections ----------------
__global__ __launch_bounds__(256) void k_lnproj(
    const float* __restrict__ x, const float* __restrict__ Wq, const float* __restrict__ bq,
    const float* __restrict__ Wk, const float* __restrict__ bk,
    const float* __restrict__ gamma, const float* __restrict__ beta,
    float* __restrict__ Xn, float* __restrict__ Qb, short* __restrict__ Kbf)
{
    __shared__ float xrow[4][64];
    int w = threadIdx.x >> 6, lane = threadIdx.x & 63;
    size_t row = (size_t)blockIdx.x * 4 + w;
    float xv = x[row * 64 + lane];
    float m = xv;
    #pragma unroll
    for (int o = 32; o; o >>= 1) m += __shfl_xor(m, o, 64);
    m *= (1.0f / 64.0f);
    float dv = xv - m;
    float var = dv * dv;
    #pragma unroll
    for (int o = 32; o; o >>= 1) var += __shfl_xor(var, o, 64);
    var *= (1.0f / 64.0f);
    float xg = dv * (1.0f / sqrtf(var + LNEPS)) * gamma[lane] + beta[lane];
    Xn[row * 64 + lane] = xg;
    xrow[w][lane] = xg;
    __syncthreads();
    float q = bq[lane], k = bk[lane];
    #pragma unroll 8
    for (int e = 0; e < 64; e++) {
        float xe = xrow[w][e];
        q += xe * Wq[e * 64 + lane];
        k += xe * Wk[e * 64 + lane];
    }
    int br = (int)(row / LL);
    int jl = (int)(row - (size_t)br * LL);
    Qb[((size_t)br * LLP + jl) * 64 + lane] = q;
    Kbf[((size_t)br * LLP + jl) * 64 + lane] = f2bf(k);
}

// ---------------- Kernel 1b: transpose Xn -> bf16 X^T, zero all pads ----------------
__global__ __launch_bounds__(256) void k_prep(
    const float* __restrict__ Xn, short* __restrict__ XbfT,
    short* __restrict__ Kbf, float* __restrict__ Qb)
{
    __shared__ float tile[64][65];
    int bb = blockIdx.x & 7;
    int jt = blockIdx.x >> 3;          // 0..38
    int j0 = jt * 64;
    for (int i = threadIdx.x; i < 4096; i += 256) {
        int jl = i >> 6, d = i & 63;
        int j = j0 + jl;
        tile[jl][d] = (j < LL) ? Xn[((size_t)bb * LL + j) * 64 + d] : 0.f;
    }
    __syncthreads();
    for (int i = threadIdx.x; i < 4096; i += 256) {
        int d = i >> 6, jl = i & 63;
        XbfT[((size_t)bb * 64 + d) * LLP + j0 + jl] = f2bf(tile[jl][d]);
    }
    if (jt == 38) {
        for (int i = threadIdx.x; i < (LLP - LL) * 64; i += 256) {
            int jl = i >> 6, d = i & 63;
            Kbf[((size_t)bb * LLP + LL + jl) * 64 + d] = 0;
            Qb [((size_t)bb * LLP + LL + jl) * 64 + d] = 0.f;
        }
    }
}

// ---------------- Kernel 2: fused attn, u8 bin-codes in LDS, RT=24 -> 2 blocks/CU ----------------
__global__ __launch_bounds__(512, 2) void k_attn(
    const float* __restrict__ Xn, const float* __restrict__ Qb,
    const short* __restrict__ Kbf, const short* __restrict__ XbfT,
    const float* __restrict__ stg, const int* __restrict__ topk_p,
    float* __restrict__ Z)
{
    __shared__ __align__(16) unsigned char Gt[RT * GCOL8];   // 59,904 B: u8 codes (g>>8)
    __shared__ __align__(16) unsigned hist[RT * 128];        // 12,288 B: 256 bins packed u16x2
    __shared__ unsigned thr_lds[RT];
    float* redf = (float*)hist;            // union: red[RT*65] + rowsum[RT], hist dead after scan
    float* rowsum = redf + RT * 65;

    int tid = threadIdx.x;
    int lane = tid & 63, wv = tid >> 6;    // wv in [0,8)
    int hi = lane >> 5, l31 = lane & 31;
    int b = blockIdx.x & 7;
    int tile = blockIdx.x >> 3;            // 0..103
    int row0 = tile * RT;

    // ---- init: Gt = 0xFF sentinel, hist = 0 ----
    for (int i = tid; i < RT * GCOL8 / 4; i += 512) ((unsigned*)Gt)[i] = 0xFFFFFFFFu;
    for (int i = tid; i < RT * 128; i += 512) hist[i] = 0u;

    int keff;
    { int tk = *topk_p; keff = (tk < 5) ? tk * NN : tk; }

    // Q A-fragments: row = row0 + l31 (rows >= RT give garbage -> discarded downstream)
    bf16x8 qf[4];
    {
        const float* qp = Qb + ((size_t)b * LLP + row0 + l31) * 64 + hi * 8;
        #pragma unroll
        for (int kk = 0; kk < 4; kk++) {
            bf16x8 f;
            #pragma unroll
            for (int e = 0; e < 8; e++) f[e] = f2bf(qp[kk * 16 + e]);
            qf[kk] = f;
        }
    }
    const float* stgb = stg + (size_t)b * LL * LL;
    int kt0 = wv * TPW;
    int kt1 = (kt0 + TPW < TILES) ? kt0 + TPW : TILES;
    __syncthreads();   // init visible

    // ---- Phase A (double-buffered): coalesced stg + MFMA -> u8 code in LDS + hist ----
    float svsA[16]; bf16x8 kvA[4];
    if (kt0 < kt1) {
        int j = kt0 * 32 + l31;
        #pragma unroll
        for (int reg = 0; reg < 16; reg++) {
            int trow = (reg & 3) + 8 * (reg >> 2) + 4 * hi;
            int grow = row0 + trow;
            bool v = (j < LL) && (trow < RT) && (grow < LL);
            svsA[reg] = v ? stgb[(size_t)grow * LL + j] : 0.f;
        }
        const short* kbase = Kbf + ((size_t)b * LLP + j) * 64 + hi * 8;
        kvA[0] = *(const bf16x8*)(kbase);
        kvA[1] = *(const bf16x8*)(kbase + 16);
        kvA[2] = *(const bf16x8*)(kbase + 32);
        kvA[3] = *(const bf16x8*)(kbase + 48);
    }
    for (int kt = kt0; kt < kt1; ++kt) {
        float svsB[16]; bf16x8 kvB[4];
        if (kt + 1 < kt1) {
            int jn = (kt + 1) * 32 + l31;
            #pragma unroll
            for (int reg = 0; reg < 16; reg++) {
                int trow = (reg & 3) + 8 * (reg >> 2) + 4 * hi;
                int grow = row0 + trow;
                bool v = (jn < LL) && (trow < RT) && (grow < LL);
                svsB[reg] = v ? stgb[(size_t)grow * LL + jn] : 0.f;
            }
            const short* kbase = Kbf + ((size_t)b * LLP + jn) * 64 + hi * 8;
            kvB[0] = *(const bf16x8*)(kbase);
            kvB[1] = *(const bf16x8*)(kbase + 16);
            kvB[2] = *(const bf16x8*)(kbase + 32);
            kvB[3] = *(const bf16x8*)(kbase + 48);
        }
        int j = kt * 32 + l31;
        bool vj = (j < LL);
        f32x16 c = {0.f,0.f,0.f,0.f,0.f,0.f,0.f,0.f,0.f,0.f,0.f,0.f,0.f,0.f,0.f,0.f};
        c = __builtin_amdgcn_mfma_f32_32x32x16_bf16(qf[0], kvA[0], c, 0, 0, 0);
        c = __builtin_amdgcn_mfma_f32_32x32x16_bf16(qf[1], kvA[1], c, 0, 0, 0);
        c = __builtin_amdgcn_mfma_f32_32x32x16_bf16(qf[2], kvA[2], c, 0, 0, 0);
        c = __builtin_amdgcn_mfma_f32_32x32x16_bf16(qf[3], kvA[3], c, 0, 0, 0);
        #pragma unroll
        for (int reg = 0; reg < 16; reg++) {
            int trow = (reg & 3) + 8 * (reg >> 2) + 4 * hi;
            int grow = row0 + trow;
            bool v = vj && (trow < RT) && (grow < LL);
            float sg = 1.0f / (1.0f + __expf(c[reg] * -0.125f));
            float s = sg * svsA[reg];
            int g = (int)(s * 65536.0f); g = (g > 65279) ? 65279 : g;   // code <= 254
            if (v) {
                unsigned code = (unsigned)g >> 8;
                Gt[trow * GCOL8 + ((unsigned)j ^ ((unsigned)(trow & 7) << 3))] = (unsigned char)code;
                atomicAdd(&hist[trow * 128 + (code >> 1)], 1u << ((code & 1) << 4));
            }
        }
        #pragma unroll
        for (int i = 0; i < 16; i++) svsA[i] = svsB[i];
        #pragma unroll
        for (int i = 0; i < 4; i++) kvA[i] = kvB[i];
    }
    __syncthreads();   // Gt + hist complete

    // ---- Phase B: 256-bin scan per row -> threshold code (keep code >= thr) ----
    #pragma unroll 1
    for (int row = wv; row < RT; row += 8) {
        const unsigned* h = &hist[row * 128];
        unsigned w0 = h[lane * 2 + 0], w1 = h[lane * 2 + 1];
        unsigned cb[4] = {w0 & 0xFFFFu, w0 >> 16, w1 & 0xFFFFu, w1 >> 16};
        unsigned S = cb[0] + cb[1] + cb[2] + cb[3];
        unsigned T = S;
        #pragma unroll
        for (int off = 1; off < 64; off <<= 1) {
            unsigned t = __shfl_down(T, off, 64);
            T += (lane + off < 64) ? t : 0u;
        }
        unsigned Tn = T - S;               // suffix starting at lane*4+4
        unsigned sfx[5];
        sfx[4] = Tn;
        #pragma unroll
        for (int i = 3; i >= 0; i--) sfx[i] = cb[i] + sfx[i + 1];
        unsigned kr = (unsigned)keff;
        int hit = -1; unsigned nk = 0, mm = 0;
        #pragma unroll
        for (int i = 0; i < 4; i++) {
            if (sfx[i] >= kr && sfx[i + 1] < kr) { hit = i; nk = kr - sfx[i + 1]; mm = cb[i]; }
        }
        unsigned long long mask = __ballot(hit >= 0);
        if (mask == 0ull) {
            if (lane == 0) thr_lds[row] = 255u;   // empty/pad row -> keep nothing
        } else {
            int src = __ffsll(mask) - 1;
            int bini = __shfl(hit, src, 64);
            nk = (unsigned)__shfl((int)nk, src, 64);
            mm = (unsigned)__shfl((int)mm, src, 64);
            if (lane == 0) {
                int bin = src * 4 + bini;
                int drop = (2u * nk <= mm && nk < kr) ? 1 : 0;   // never empties kept set
                thr_lds[row] = (unsigned)(bin + drop);
            }
        }
    }
    __syncthreads();   // scans done reading hist

    // ---- re-purpose hist region as PV accumulators ----
    for (int i = tid; i < RT * 65 + RT; i += 512) redf[i] = 0.f;
    __syncthreads();

    // ---- Phase C (double-buffered): PV from u8 codes (weight = exp((code+0.5)/256)) ----
    bool av = (l31 < RT);
    int arow = av ? l31 : 0;
    unsigned athr = av ? thr_lds[arow] : 255u;
    unsigned swz = ((unsigned)(arow & 7)) << 3;
    const unsigned char* gp8 = &Gt[arow * GCOL8];
    const short* xb0 = XbfT + ((size_t)b * 64 + l31) * LLP + hi * 8;
    const short* xb1 = XbfT + ((size_t)b * 64 + 32 + l31) * LLP + hi * 8;
    f32x16 p0 = {0.f,0.f,0.f,0.f,0.f,0.f,0.f,0.f,0.f,0.f,0.f,0.f,0.f,0.f,0.f,0.f};
    f32x16 p1 = p0;
    float smr = 0.f;

    bf16x8 xA[4];
    if (kt0 < kt1) {
        int j0 = kt0 * 32;
        xA[0] = *(const bf16x8*)(xb0 + j0);
        xA[1] = *(const bf16x8*)(xb0 + j0 + 16);
        xA[2] = *(const bf16x8*)(xb1 + j0);
        xA[3] = *(const bf16x8*)(xb1 + j0 + 16);
    }
    for (int kt = kt0; kt < kt1; ++kt) {
        bf16x8 xB[4];
        if (kt + 1 < kt1) {
            int jn = (kt + 1) * 32;
            xB[0] = *(const bf16x8*)(xb0 + jn);
            xB[1] = *(const bf16x8*)(xb0 + jn + 16);
            xB[2] = *(const bf16x8*)(xb1 + jn);
            xB[3] = *(const bf16x8*)(xb1 + jn + 16);
        }
        int j0 = kt * 32;
        bf16x8 ea[2];
        #pragma unroll
        for (int kk = 0; kk < 2; kk++) {
            u8x8 gv = *(const u8x8*)&gp8[(unsigned)(j0 + kk * 16 + hi * 8) ^ swz];
            bf16x8 f;
            #pragma unroll
            for (int e = 0; e < 8; e++) {
                unsigned g = gv[e];
                bool keep = (g >= athr) && (g != 255u);
                float ev = keep ? __expf(((float)g + 0.5f) * 0.00390625f) : 0.f;
                smr += ev;
                f[e] = f2bf(ev);
            }
            ea[kk] = f;
        }
        p0 = __builtin_amdgcn_mfma_f32_32x32x16_bf16(ea[0], xA[0], p0, 0, 0, 0);
        p0 = __builtin_amdgcn_mfma_f32_32x32x16_bf16(ea[1], xA[1], p0, 0, 0, 0);
        p1 = __builtin_amdgcn_mfma_f32_32x32x16_bf16(ea[0], xA[2], p1, 0, 0, 0);
        p1 = __builtin_amdgcn_mfma_f32_32x32x16_bf16(ea[1], xA[3], p1, 0, 0, 0);
        #pragma unroll
        for (int i = 0; i < 4; i++) xA[i] = xB[i];
    }
    smr += __shfl_xor(smr, 32, 64);
    if (lane < 32 && l31 < RT) atomicAdd(&rowsum[l31], smr);
    #pragma unroll
    for (int reg = 0; reg < 16; reg++) {
        int trow = (reg & 3) + 8 * (reg >> 2) + 4 * hi;
        if (trow < RT) {
            atomicAdd(&redf[trow * 65 + l31],      p0[reg]);
            atomicAdd(&redf[trow * 65 + 32 + l31], p1[reg]);
        }
    }
    __syncthreads();

    // ---- epilogue: normalize + residual ----
    for (int i = tid; i < RT * 64; i += 512) {
        int r = i >> 6, d = i & 63;
        int grow = row0 + r;
        if (grow < LL) {
            size_t gi = ((size_t)b * LL + grow) * 64 + d;
            Z[gi] = redf[r * 65 + d] * (1.0f / rowsum[r]) + Xn[gi];
        }
    }
}

// ---------------- Kernel 3: fused LN + FFN + residual ----------------
__global__ __launch_bounds__(256) void k_ffn(
    const float* __restrict__ Zb, const float* __restrict__ fg, const float* __restrict__ fb,
    const float* __restrict__ w1, const float* __restrict__ b1,
    const float* __restrict__ w2, const float* __restrict__ b2,
    float* __restrict__ out)
{
    const int G2 = 16;
    __shared__ float zr[G2][64];
    __shared__ float zl[G2][64];
    __shared__ float h[G2][DHID];
    int tid = threadIdx.x;
    int w = tid >> 6, lane = tid & 63;
    size_t row0 = (size_t)blockIdx.x * G2;
    for (int rr = w; rr < G2; rr += 4) {
        float zv = Zb[(row0 + rr) * 64 + lane];
        zr[rr][lane] = zv;
        float m = zv;
        #pragma unroll
        for (int o = 32; o; o >>= 1) m += __shfl_xor(m, o, 64);
        m *= (1.0f / 64.0f);
        float dv = zv - m;
        float var = dv * dv;
        #pragma unroll
        for (int o = 32; o; o >>= 1) var += __shfl_xor(var, o, 64);
        var *= (1.0f / 64.0f);
        zl[rr][lane] = dv * (1.0f / sqrtf(var + LNEPS)) * fg[lane] + fb[lane];
    }
    __syncthreads();
    float hacc[G2];
    #pragma unroll
    for (int g = 0; g < G2; g++) hacc[g] = 0.f;
    for (int d = 0; d < 64; d++) {
        float wv1 = w1[d * DHID + tid];
        #pragma unroll
        for (int g = 0; g < G2; g++) hacc[g] += zl[g][d] * wv1;
    }
    float b1v = b1[tid];
    #pragma unroll
    for (int g = 0; g < G2; g++) h[g][tid] = fmaxf(hacc[g] + b1v, 0.f);
    __syncthreads();
    float oacc[4] = {0.f, 0.f, 0.f, 0.f};
    for (int i = 0; i < DHID; i++) {
        float wv2 = w2[i * 64 + lane];
        #pragma unroll
        for (int rr = 0; rr < 4; rr++) oacc[rr] += h[w * 4 + rr][i] * wv2;
    }
    float b2v = b2[lane];
    #pragma unroll
    for (int rr = 0; rr < 4; rr++)
        out[(row0 + w * 4 + rr) * 64 + lane] = zr[w * 4 + rr][lane] + oacc[rr] + b2v;
}

extern "C" void kernel_launch(void* const* d_in, const int* in_sizes, int n_in,
                              void* d_out, int out_size, void* d_ws, size_t ws_size,
                              hipStream_t stream)
{
    const float* x      = (const float*)d_in[0];
    const float* stg    = (const float*)d_in[1];
    const float* Wq     = (const float*)d_in[2];
    const float* bq     = (const float*)d_in[3];
    const float* Wk     = (const float*)d_in[4];
    const float* bk     = (const float*)d_in[5];
    const float* gamma  = (const float*)d_in[6];
    const float* beta   = (const float*)d_in[7];
    const float* fgamma = (const float*)d_in[8];
    const float* fbeta  = (const float*)d_in[9];
    const float* w1     = (const float*)d_in[10];
    const float* b1     = (const float*)d_in[11];
    const float* w2     = (const float*)d_in[12];
    const float* b2     = (const float*)d_in[13];
    const int*   topk   = (const int*)d_in[14];
    float* out = (float*)d_out;

    const size_t rows  = (size_t)NBATCH * LL;    // 19872
    const size_t prows = (size_t)NBATCH * LLP;   // 19968
    float* Xn = (float*)d_ws;                    // rows*64 f32
    float* Qb = Xn + rows * 64;                  // (prows+64)*64 f32 (padded + tile-overrun slack)
    float* Z  = Qb + (prows + 64) * 64;          // rows*64 f32
    short* Kbf  = (short*)(Z + rows * 64);       // prows*64 bf16
    short* XbfT = Kbf + prows * 64;              // prows*64 bf16 (transposed layout)
    // total ~20.4 MB — proven ws budget

    k_lnproj<<<(int)(rows / 4), 256, 0, stream>>>(x, Wq, bq, Wk, bk, gamma, beta, Xn, Qb, Kbf);
    k_prep<<<NBATCH * 39, 256, 0, stream>>>(Xn, XbfT, Kbf, Qb);
    k_attn<<<NBATCH * NBLK, 512, 0, stream>>>(Xn, Qb, Kbf, XbfT, stg, topk, Z);
    k_ffn<<<(int)(rows / 16), 256, 0, stream>>>(Z, fgamma, fbeta, w1, b1, w2, b2, out);
}

// Round 22
// 230.460 us; speedup vs baseline: 1.1534x; 1.1534x over previous
//
#include <hip/hip_runtime.h>

#define NBATCH 8
#define NN     207
#define DHID   256
#define LL     2484      // 12*207
#define LLP    2496      // padded to multiple of 32
#define RT     26        // query rows per block (96 blocks/batch: 96*26=2496)
#define NBLK   96
#define GCOL8  2496      // u8 G-tile cols
#define TILES  78        // LLP/32
#define TPW    10        // j-tiles per wave (8 waves x 10 >= 78)
#define LNEPS  1e-5f

typedef __attribute__((ext_vector_type(8)))  short bf16x8;
typedef __attribute__((ext_vector_type(8)))  unsigned char u8x8;
typedef __attribute__((ext_vector_type(16))) float f32x16;

__device__ __forceinline__ short f2bf(float f) {
    unsigned u = __float_as_uint(f);
    unsigned r = (u + 0x7FFFu + ((u >> 16) & 1u)) >> 16;
    return (short)r;
}

// ---------------- Kernel 1: LayerNorm + Q/K projections ----------------
__global__ __launch_bounds__(256) void k_lnproj(
    const float* __restrict__ x, const float* __restrict__ Wq, const float* __restrict__ bq,
    const float* __restrict__ Wk, const float* __restrict__ bk,
    const float* __restrict__ gamma, const float* __restrict__ beta,
    float* __restrict__ Xn, float* __restrict__ Qb, short* __restrict__ Kbf)
{
    __shared__ float xrow[4][64];
    int w = threadIdx.x >> 6, lane = threadIdx.x & 63;
    size_t row = (size_t)blockIdx.x * 4 + w;
    float xv = x[row * 64 + lane];
    float m = xv;
    #pragma unroll
    for (int o = 32; o; o >>= 1) m += __shfl_xor(m, o, 64);
    m *= (1.0f / 64.0f);
    float dv = xv - m;
    float var = dv * dv;
    #pragma unroll
    for (int o = 32; o; o >>= 1) var += __shfl_xor(var, o, 64);
    var *= (1.0f / 64.0f);
    float xg = dv * (1.0f / sqrtf(var + LNEPS)) * gamma[lane] + beta[lane];
    Xn[row * 64 + lane] = xg;
    xrow[w][lane] = xg;
    __syncthreads();
    float q = bq[lane], k = bk[lane];
    #pragma unroll 8
    for (int e = 0; e < 64; e++) {
        float xe = xrow[w][e];
        q += xe * Wq[e * 64 + lane];
        k += xe * Wk[e * 64 + lane];
    }
    int br = (int)(row / LL);
    int jl = (int)(row - (size_t)br * LL);
    Qb[((size_t)br * LLP + jl) * 64 + lane] = q;
    Kbf[((size_t)br * LLP + jl) * 64 + lane] = f2bf(k);
}

// ---------------- Kernel 1b: transpose Xn -> bf16 X^T, zero all pads ----------------
__global__ __launch_bounds__(256) void k_prep(
    const float* __restrict__ Xn, short* __restrict__ XbfT,
    short* __restrict__ Kbf, float* __restrict__ Qb)
{
    __shared__ float tile[64][65];
    int bb = blockIdx.x & 7;
    int jt = blockIdx.x >> 3;          // 0..38
    int j0 = jt * 64;
    for (int i = threadIdx.x; i < 4096; i += 256) {
        int jl = i >> 6, d = i & 63;
        int j = j0 + jl;
        tile[jl][d] = (j < LL) ? Xn[((size_t)bb * LL + j) * 64 + d] : 0.f;
    }
    __syncthreads();
    for (int i = threadIdx.x; i < 4096; i += 256) {
        int d = i >> 6, jl = i & 63;
        XbfT[((size_t)bb * 64 + d) * LLP + j0 + jl] = f2bf(tile[jl][d]);
    }
    if (jt == 38) {
        for (int i = threadIdx.x; i < (LLP - LL) * 64; i += 256) {
            int jl = i >> 6, d = i & 63;
            Kbf[((size_t)bb * LLP + LL + jl) * 64 + d] = 0;
            Qb [((size_t)bb * LLP + LL + jl) * 64 + d] = 0.f;
        }
    }
}

// ---------------- Kernel 2: fused attn, u8 bin-codes in LDS ----------------
__global__ __launch_bounds__(512, 2) void k_attn(
    const float* __restrict__ Xn, const float* __restrict__ Qb,
    const short* __restrict__ Kbf, const short* __restrict__ XbfT,
    const float* __restrict__ stg, const int* __restrict__ topk_p,
    float* __restrict__ Z)
{
    __shared__ __align__(16) unsigned char Gt[RT * GCOL8];   // 64,896 B: u8 codes (g>>8)
    __shared__ __align__(16) unsigned hist[RT * 128];        // 13,312 B: 256 bins packed u16x2
    __shared__ unsigned thr_lds[RT];
    float* redf = (float*)hist;            // union: red[RT*65] + rowsum[RT], hist dead after scan
    float* rowsum = redf + RT * 65;

    int tid = threadIdx.x;
    int lane = tid & 63, wv = tid >> 6;    // wv in [0,8)
    int hi = lane >> 5, l31 = lane & 31;
    int b = blockIdx.x & 7;
    int tile = blockIdx.x >> 3;            // 0..95
    int row0 = tile * RT;

    // ---- init: Gt = 0xFF sentinel, hist = 0 ----
    for (int i = tid; i < RT * GCOL8 / 4; i += 512) ((unsigned*)Gt)[i] = 0xFFFFFFFFu;
    for (int i = tid; i < RT * 128; i += 512) hist[i] = 0u;

    int keff;
    { int tk = *topk_p; keff = (tk < 5) ? tk * NN : tk; }

    // Q A-fragments: row = row0 + l31 (rows >= RT give garbage -> discarded downstream)
    bf16x8 qf[4];
    {
        const float* qp = Qb + ((size_t)b * LLP + row0 + l31) * 64 + hi * 8;
        #pragma unroll
        for (int kk = 0; kk < 4; kk++) {
            bf16x8 f;
            #pragma unroll
            for (int e = 0; e < 8; e++) f[e] = f2bf(qp[kk * 16 + e]);
            qf[kk] = f;
        }
    }
    const float* stgb = stg + (size_t)b * LL * LL;
    int kt0 = wv * TPW;
    int kt1 = (kt0 + TPW < TILES) ? kt0 + TPW : TILES;
    __syncthreads();   // init visible

    // ---- Phase A (double-buffered): coalesced stg + MFMA -> u8 code in LDS + hist ----
    float svsA[16]; bf16x8 kvA[4];
    if (kt0 < kt1) {
        int j = kt0 * 32 + l31;
        #pragma unroll
        for (int reg = 0; reg < 16; reg++) {
            int trow = (reg & 3) + 8 * (reg >> 2) + 4 * hi;
            int grow = row0 + trow;
            bool v = (j < LL) && (trow < RT) && (grow < LL);
            svsA[reg] = v ? stgb[(size_t)grow * LL + j] : 0.f;
        }
        const short* kbase = Kbf + ((size_t)b * LLP + j) * 64 + hi * 8;
        kvA[0] = *(const bf16x8*)(kbase);
        kvA[1] = *(const bf16x8*)(kbase + 16);
        kvA[2] = *(const bf16x8*)(kbase + 32);
        kvA[3] = *(const bf16x8*)(kbase + 48);
    }
    for (int kt = kt0; kt < kt1; ++kt) {
        float svsB[16]; bf16x8 kvB[4];
        if (kt + 1 < kt1) {
            int jn = (kt + 1) * 32 + l31;
            #pragma unroll
            for (int reg = 0; reg < 16; reg++) {
                int trow = (reg & 3) + 8 * (reg >> 2) + 4 * hi;
                int grow = row0 + trow;
                bool v = (jn < LL) && (trow < RT) && (grow < LL);
                svsB[reg] = v ? stgb[(size_t)grow * LL + jn] : 0.f;
            }
            const short* kbase = Kbf + ((size_t)b * LLP + jn) * 64 + hi * 8;
            kvB[0] = *(const bf16x8*)(kbase);
            kvB[1] = *(const bf16x8*)(kbase + 16);
            kvB[2] = *(const bf16x8*)(kbase + 32);
            kvB[3] = *(const bf16x8*)(kbase + 48);
        }
        int j = kt * 32 + l31;
        bool vj = (j < LL);
        f32x16 c = {0.f,0.f,0.f,0.f,0.f,0.f,0.f,0.f,0.f,0.f,0.f,0.f,0.f,0.f,0.f,0.f};
        c = __builtin_amdgcn_mfma_f32_32x32x16_bf16(qf[0], kvA[0], c, 0, 0, 0);
        c = __builtin_amdgcn_mfma_f32_32x32x16_bf16(qf[1], kvA[1], c, 0, 0, 0);
        c = __builtin_amdgcn_mfma_f32_32x32x16_bf16(qf[2], kvA[2], c, 0, 0, 0);
        c = __builtin_amdgcn_mfma_f32_32x32x16_bf16(qf[3], kvA[3], c, 0, 0, 0);
        #pragma unroll
        for (int reg = 0; reg < 16; reg++) {
            int trow = (reg & 3) + 8 * (reg >> 2) + 4 * hi;
            int grow = row0 + trow;
            bool v = vj && (trow < RT) && (grow < LL);
            float sg = 1.0f / (1.0f + __expf(c[reg] * -0.125f));
            float s = sg * svsA[reg];
            int g = (int)(s * 65536.0f); g = (g > 65279) ? 65279 : g;   // code <= 254
            if (v) {
                unsigned code = (unsigned)g >> 8;
                Gt[trow * GCOL8 + ((unsigned)j ^ ((unsigned)(trow & 7) << 3))] = (unsigned char)code;
                atomicAdd(&hist[trow * 128 + (code >> 1)], 1u << ((code & 1) << 4));
            }
        }
        #pragma unroll
        for (int i = 0; i < 16; i++) svsA[i] = svsB[i];
        #pragma unroll
        for (int i = 0; i < 4; i++) kvA[i] = kvB[i];
    }
    __syncthreads();   // Gt + hist complete

    // ---- Phase B: 256-bin scan per row -> threshold code (keep code >= thr) ----
    #pragma unroll 1
    for (int row = wv; row < RT; row += 8) {
        const unsigned* h = &hist[row * 128];
        unsigned w0 = h[lane * 2 + 0], w1 = h[lane * 2 + 1];
        unsigned cb[4] = {w0 & 0xFFFFu, w0 >> 16, w1 & 0xFFFFu, w1 >> 16};
        unsigned S = cb[0] + cb[1] + cb[2] + cb[3];
        unsigned T = S;
        #pragma unroll
        for (int off = 1; off < 64; off <<= 1) {
            unsigned t = __shfl_down(T, off, 64);
            T += (lane + off < 64) ? t : 0u;
        }
        unsigned Tn = T - S;               // suffix starting at lane*4+4
        unsigned sfx[5];
        sfx[4] = Tn;
        #pragma unroll
        for (int i = 3; i >= 0; i--) sfx[i] = cb[i] + sfx[i + 1];
        unsigned kr = (unsigned)keff;
        int hit = -1; unsigned nk = 0, mm = 0;
        #pragma unroll
        for (int i = 0; i < 4; i++) {
            if (sfx[i] >= kr && sfx[i + 1] < kr) { hit = i; nk = kr - sfx[i + 1]; mm = cb[i]; }
        }
        unsigned long long mask = __ballot(hit >= 0);
        if (mask == 0ull) {
            if (lane == 0) thr_lds[row] = 255u;   // empty/pad row -> keep nothing
        } else {
            int src = __ffsll(mask) - 1;
            int bini = __shfl(hit, src, 64);
            nk = (unsigned)__shfl((int)nk, src, 64);
            mm = (unsigned)__shfl((int)mm, src, 64);
            if (lane == 0) {
                int bin = src * 4 + bini;
                int drop = (2u * nk <= mm && nk < kr) ? 1 : 0;   // never empties kept set
                thr_lds[row] = (unsigned)(bin + drop);
            }
        }
    }
    __syncthreads();   // scans done reading hist

    // ---- re-purpose hist region as PV accumulators ----
    for (int i = tid; i < RT * 65 + RT; i += 512) redf[i] = 0.f;
    __syncthreads();

    // ---- Phase C (double-buffered): PV from u8 codes (weight = exp((code+0.5)/256)) ----
    bool av = (l31 < RT);
    int arow = av ? l31 : 0;
    unsigned athr = av ? thr_lds[arow] : 255u;
    unsigned swz = ((unsigned)(arow & 7)) << 3;
    const unsigned char* gp8 = &Gt[arow * GCOL8];
    const short* xb0 = XbfT + ((size_t)b * 64 + l31) * LLP + hi * 8;
    const short* xb1 = XbfT + ((size_t)b * 64 + 32 + l31) * LLP + hi * 8;
    f32x16 p0 = {0.f,0.f,0.f,0.f,0.f,0.f,0.f,0.f,0.f,0.f,0.f,0.f,0.f,0.f,0.f,0.f};
    f32x16 p1 = p0;
    float smr = 0.f;

    bf16x8 xA[4];
    if (kt0 < kt1) {
        int j0 = kt0 * 32;
        xA[0] = *(const bf16x8*)(xb0 + j0);
        xA[1] = *(const bf16x8*)(xb0 + j0 + 16);
        xA[2] = *(const bf16x8*)(xb1 + j0);
        xA[3] = *(const bf16x8*)(xb1 + j0 + 16);
    }
    for (int kt = kt0; kt < kt1; ++kt) {
        bf16x8 xB[4];
        if (kt + 1 < kt1) {
            int jn = (kt + 1) * 32;
            xB[0] = *(const bf16x8*)(xb0 + jn);
            xB[1] = *(const bf16x8*)(xb0 + jn + 16);
            xB[2] = *(const bf16x8*)(xb1 + jn);
            xB[3] = *(const bf16x8*)(xb1 + jn + 16);
        }
        int j0 = kt * 32;
        bf16x8 ea[2];
        #pragma unroll
        for (int kk = 0; kk < 2; kk++) {
            u8x8 gv = *(const u8x8*)&gp8[(unsigned)(j0 + kk * 16 + hi * 8) ^ swz];
            bf16x8 f;
            #pragma unroll
            for (int e = 0; e < 8; e++) {
                unsigned g = gv[e];
                bool keep = (g >= athr) && (g != 255u);
                float ev = keep ? __expf(((float)g + 0.5f) * 0.00390625f) : 0.f;
                smr += ev;
                f[e] = f2bf(ev);
            }
            ea[kk] = f;
        }
        p0 = __builtin_amdgcn_mfma_f32_32x32x16_bf16(ea[0], xA[0], p0, 0, 0, 0);
        p0 = __builtin_amdgcn_mfma_f32_32x32x16_bf16(ea[1], xA[1], p0, 0, 0, 0);
        p1 = __builtin_amdgcn_mfma_f32_32x32x16_bf16(ea[0], xA[2], p1, 0, 0, 0);
        p1 = __builtin_amdgcn_mfma_f32_32x32x16_bf16(ea[1], xA[3], p1, 0, 0, 0);
        #pragma unroll
        for (int i = 0; i < 4; i++) xA[i] = xB[i];
    }
    smr += __shfl_xor(smr, 32, 64);
    if (lane < 32 && l31 < RT) atomicAdd(&rowsum[l31], smr);
    #pragma unroll
    for (int reg = 0; reg < 16; reg++) {
        int trow = (reg & 3) + 8 * (reg >> 2) + 4 * hi;
        if (trow < RT) {
            atomicAdd(&redf[trow * 65 + l31],      p0[reg]);
            atomicAdd(&redf[trow * 65 + 32 + l31], p1[reg]);
        }
    }
    __syncthreads();

    // ---- epilogue: normalize + residual ----
    for (int i = tid; i < RT * 64; i += 512) {
        int r = i >> 6, d = i & 63;
        int grow = row0 + r;
        if (grow < LL) {
            size_t gi = ((size_t)b * LL + grow) * 64 + d;
            Z[gi] = redf[r * 65 + d] * (1.0f / rowsum[r]) + Xn[gi];
        }
    }
}

// ---------------- Kernel 3: fused LN + FFN + residual ----------------
__global__ __launch_bounds__(256) void k_ffn(
    const float* __restrict__ Zb, const float* __restrict__ fg, const float* __restrict__ fb,
    const float* __restrict__ w1, const float* __restrict__ b1,
    const float* __restrict__ w2, const float* __restrict__ b2,
    float* __restrict__ out)
{
    const int G2 = 16;
    __shared__ float zr[G2][64];
    __shared__ float zl[G2][64];
    __shared__ float h[G2][DHID];
    int tid = threadIdx.x;
    int w = tid >> 6, lane = tid & 63;
    size_t row0 = (size_t)blockIdx.x * G2;
    for (int rr = w; rr < G2; rr += 4) {
        float zv = Zb[(row0 + rr) * 64 + lane];
        zr[rr][lane] = zv;
        float m = zv;
        #pragma unroll
        for (int o = 32; o; o >>= 1) m += __shfl_xor(m, o, 64);
        m *= (1.0f / 64.0f);
        float dv = zv - m;
        float var = dv * dv;
        #pragma unroll
        for (int o = 32; o; o >>= 1) var += __shfl_xor(var, o, 64);
        var *= (1.0f / 64.0f);
        zl[rr][lane] = dv * (1.0f / sqrtf(var + LNEPS)) * fg[lane] + fb[lane];
    }
    __syncthreads();
    float hacc[G2];
    #pragma unroll
    for (int g = 0; g < G2; g++) hacc[g] = 0.f;
    for (int d = 0; d < 64; d++) {
        float wv1 = w1[d * DHID + tid];
        #pragma unroll
        for (int g = 0; g < G2; g++) hacc[g] += zl[g][d] * wv1;
    }
    float b1v = b1[tid];
    #pragma unroll
    for (int g = 0; g < G2; g++) h[g][tid] = fmaxf(hacc[g] + b1v, 0.f);
    __syncthreads();
    float oacc[4] = {0.f, 0.f, 0.f, 0.f};
    for (int i = 0; i < DHID; i++) {
        float wv2 = w2[i * 64 + lane];
        #pragma unroll
        for (int rr = 0; rr < 4; rr++) oacc[rr] += h[w * 4 + rr][i] * wv2;
    }
    float b2v = b2[lane];
    #pragma unroll
    for (int rr = 0; rr < 4; rr++)
        out[(row0 + w * 4 + rr) * 64 + lane] = zr[w * 4 + rr][lane] + oacc[rr] + b2v;
}

extern "C" void kernel_launch(void* const* d_in, const int* in_sizes, int n_in,
                              void* d_out, int out_size, void* d_ws, size_t ws_size,
                              hipStream_t stream)
{
    const float* x      = (const float*)d_in[0];
    const float* stg    = (const float*)d_in[1];
    const float* Wq     = (const float*)d_in[2];
    const float* bq     = (const float*)d_in[3];
    const float* Wk     = (const float*)d_in[4];
    const float* bk     = (const float*)d_in[5];
    const float* gamma  = (const float*)d_in[6];
    const float* beta   = (const float*)d_in[7];
    const float* fgamma = (const float*)d_in[8];
    const float* fbeta  = (const float*)d_in[9];
    const float* w1     = (const float*)d_in[10];
    const float* b1     = (const float*)d_in[11];
    const float* w2     = (const float*)d_in[12];
    const float* b2     = (const float*)d_in[13];
    const int*   topk   = (const int*)d_in[14];
    float* out = (float*)d_out;

    const size_t rows  = (size_t)NBATCH * LL;    // 19872
    const size_t prows = (size_t)NBATCH * LLP;   // 19968
    float* Xn = (float*)d_ws;                    // rows*64 f32
    float* Qb = Xn + rows * 64;                  // (prows+64)*64 f32 (padded + tile-overrun slack)
    float* Z  = Qb + (prows + 64) * 64;          // rows*64 f32
    short* Kbf  = (short*)(Z + rows * 64);       // prows*64 bf16
    short* XbfT = Kbf + prows * 64;              // prows*64 bf16 (transposed layout)
    // total ~20.4 MB — proven ws budget

    k_lnproj<<<(int)(rows / 4), 256, 0, stream>>>(x, Wq, bq, Wk, bk, gamma, beta, Xn, Qb, Kbf);
    k_prep<<<NBATCH * 39, 256, 0, stream>>>(Xn, XbfT, Kbf, Qb);
    k_attn<<<NBATCH * NBLK, 512, 0, stream>>>(Xn, Qb, Kbf, XbfT, stg, topk, Z);
    k_ffn<<<(int)(rows / 16), 256, 0, stream>>>(Z, fgamma, fbeta, w1, b1, w2, b2, out);
}